// Round 1
// baseline (359.155 us; speedup 1.0000x reference)
//
#include <hip/hip_runtime.h>
#include <stdint.h>

// Problem constants: B=32, T=128, C=64, DIN=DOUT=32, 4 gates.
#define T_STEPS 128
#define C_CH    64
#define D_IN    32
#define D_OUT   32

// LDS row stride in shorts for bf16 planes: 64 data + 8 pad (keeps 16B row
// alignment for ds_read_b128 and spreads banks).
#define RS 72

using frag_ab = __attribute__((ext_vector_type(8))) short;  // 8 bf16
using frag_cd = __attribute__((ext_vector_type(4))) float;  // 4 fp32 acc

// CK-style workgroup barrier that drains only LDS (lgkmcnt), leaving global
// prefetch loads in flight across the barrier (avoids the vmcnt(0) drain
// __syncthreads() would emit).
__device__ __forceinline__ void lds_barrier() {
  asm volatile("s_waitcnt lgkmcnt(0)\n\ts_barrier" ::: "memory");
}

// Pack the high 16 bits (bf16 truncation) of two fp32 bit patterns:
// low short = u0[31:16], high short = u1[31:16].
__device__ __forceinline__ uint32_t pack_hi16(uint32_t u0, uint32_t u1) {
  return __builtin_amdgcn_perm(u1, u0, 0x07060302u);
}

__device__ __forceinline__ float fast_sigmoid(float v) {
  return __builtin_amdgcn_rcpf(1.0f + __expf(-v));
}
__device__ __forceinline__ float fast_tanh(float v) {
  return fmaf(2.0f, __builtin_amdgcn_rcpf(1.0f + __expf(-2.0f * v)), -1.0f);
}

// Grid: 256 blocks = batch-quarter q (0..3) * 64 + channel c.  (q*64+c keeps
// all 4 WGs of one channel on the same XCD under round-robin dispatch, so the
// 4x redundant weight reads hit that XCD's L2.)
// Block: 256 threads = 4 waves; wave w computes gate w.
__global__ void __launch_bounds__(256)
lstm_kernel(const float* __restrict__ x, const float* __restrict__ xOps,
            const float* __restrict__ hOps, float* __restrict__ out) {
  __shared__ short Ahi[128 * RS];   // weights hi-bf16, rows m = g*32+i, k in [0,64)
  __shared__ short Alo[128 * RS];   // weights lo-bf16 (residual)
  __shared__ short Bhi[16 * RS];    // [x_t ; h] hi, rows n = local batch (8 valid)
  __shared__ short Blo[16 * RS];
  __shared__ float exch[4 * 32 * 9];  // gate pre-activations [g][i][b], stride 9

  const int tid = threadIdx.x;
  const int c   = blockIdx.x & 63;
  const int q   = blockIdx.x >> 6;

  // Zero B planes: h starts at 0; pad rows n=8..15 stay 0 forever.
  for (int idx = tid; idx < (16 * RS) / 2; idx += 256) {
    ((uint32_t*)Bhi)[idx] = 0u;
    ((uint32_t*)Blo)[idx] = 0u;
  }

  // Per-thread weight staging addresses (t-invariant). 8192 floats/step =
  // 256 threads * 8 float4 loads, fully coalesced in flat order.
  const float* wptr[8];
  int wlds[8];
#pragma unroll
  for (int it = 0; it < 8; ++it) {
    int f  = (it * 256 + tid) * 4;  // flat float idx in [0, 8192)
    int fh = f & 4095;
    int g  = fh >> 10;
    int i  = (fh >> 5) & 31;
    int j  = fh & 31;               // multiple of 4
    const float* base = (f < 4096) ? xOps : hOps;
    wptr[it] = base + (size_t)g * (T_STEPS * C_CH * 1024) + (size_t)c * 1024 + i * 32 + j;
    int k = j + ((f < 4096) ? 0 : 32);
    wlds[it] = (g * 32 + i) * RS + k;
  }

  // x staging: threads 0..127 each load a float2 of x_t for (b local, k pair).
  const float* xptr = x;
  int xlds = 0;
  if (tid < 128) {
    int bl = tid >> 4;
    int kp = (tid & 15) * 2;
    int bg = q * 8 + bl;
    xptr = x + (size_t)bg * (T_STEPS * C_CH * D_IN) + (size_t)c * D_IN + kp;
    xlds = bl * RS + kp;
  }

  const int wave   = tid >> 6;   // gate
  const int lane   = tid & 63;
  const int frag_n = lane & 15;
  const int quad   = lane >> 4;

  const int eb = tid >> 5;       // elementwise: local batch 0..7
  const int ei = tid & 31;       // elementwise: output dim

  // Prefetch t=0 into registers.
  float4 wv[8];
#pragma unroll
  for (int it = 0; it < 8; ++it) wv[it] = *(const float4*)wptr[it];
  float2 xv = make_float2(0.f, 0.f);
  if (tid < 128) xv = *(const float2*)xptr;

  lds_barrier();  // B-zeroing ordered before first writes/reads

  float c_state = 0.0f;

#pragma unroll 1
  for (int t = 0; t < T_STEPS; ++t) {
    // ---- stage weights: fp32 -> (hi,lo) bf16 split, write to LDS ----
    // hi = trunc16(f); lo = trunc16(f - hi)  => pair represents f to ~2^-16 rel.
#pragma unroll
    for (int it = 0; it < 8; ++it) {
      float4 v = wv[it];
      uint32_t u0 = __float_as_uint(v.x), u1 = __float_as_uint(v.y);
      uint32_t u2 = __float_as_uint(v.z), u3 = __float_as_uint(v.w);
      float r0 = v.x - __uint_as_float(u0 & 0xFFFF0000u);
      float r1 = v.y - __uint_as_float(u1 & 0xFFFF0000u);
      float r2 = v.z - __uint_as_float(u2 & 0xFFFF0000u);
      float r3 = v.w - __uint_as_float(u3 & 0xFFFF0000u);
      int s = wlds[it];
      *(uint2*)&Ahi[s] = make_uint2(pack_hi16(u0, u1), pack_hi16(u2, u3));
      *(uint2*)&Alo[s] = make_uint2(pack_hi16(__float_as_uint(r0), __float_as_uint(r1)),
                                    pack_hi16(__float_as_uint(r2), __float_as_uint(r3)));
    }
    if (tid < 128) {
      uint32_t u0 = __float_as_uint(xv.x), u1 = __float_as_uint(xv.y);
      float r0 = xv.x - __uint_as_float(u0 & 0xFFFF0000u);
      float r1 = xv.y - __uint_as_float(u1 & 0xFFFF0000u);
      *(uint32_t*)&Bhi[xlds] = pack_hi16(u0, u1);
      *(uint32_t*)&Blo[xlds] = pack_hi16(__float_as_uint(r0), __float_as_uint(r1));
    }

    // ---- issue prefetch for t+1; stays in flight across lgkm-only barriers ----
    if (t + 1 < T_STEPS) {
#pragma unroll
      for (int it = 0; it < 8; ++it)
        wv[it] = *(const float4*)(wptr[it] + (size_t)(t + 1) * (C_CH * 1024));
      if (tid < 128) xv = *(const float2*)(xptr + (size_t)(t + 1) * (C_CH * D_IN));
    }

    lds_barrier();

    // ---- MFMA: X[g] = [xop_g | hop_g] * [x_t ; h], 3-term hi/lo split ----
    // A frag: A[m = lane&15][k = quad*8 + j]; B frag: B[k = quad*8 + j][n = lane&15]
    frag_cd acc0 = {0.f, 0.f, 0.f, 0.f};
    frag_cd acc1 = {0.f, 0.f, 0.f, 0.f};
#pragma unroll
    for (int kt = 0; kt < 2; ++kt) {
      const int kk = kt * 32 + quad * 8;
      frag_ab bh = *(const frag_ab*)&Bhi[frag_n * RS + kk];
      frag_ab bl = *(const frag_ab*)&Blo[frag_n * RS + kk];
      {
        int m = wave * 32 + frag_n;            // M-tile 0 of this gate
        frag_ab ah = *(const frag_ab*)&Ahi[m * RS + kk];
        frag_ab al = *(const frag_ab*)&Alo[m * RS + kk];
        acc0 = __builtin_amdgcn_mfma_f32_16x16x32_bf16(ah, bh, acc0, 0, 0, 0);
        acc0 = __builtin_amdgcn_mfma_f32_16x16x32_bf16(ah, bl, acc0, 0, 0, 0);
        acc0 = __builtin_amdgcn_mfma_f32_16x16x32_bf16(al, bh, acc0, 0, 0, 0);
      }
      {
        int m = wave * 32 + 16 + frag_n;       // M-tile 1
        frag_ab ah = *(const frag_ab*)&Ahi[m * RS + kk];
        frag_ab al = *(const frag_ab*)&Alo[m * RS + kk];
        acc1 = __builtin_amdgcn_mfma_f32_16x16x32_bf16(ah, bh, acc1, 0, 0, 0);
        acc1 = __builtin_amdgcn_mfma_f32_16x16x32_bf16(ah, bl, acc1, 0, 0, 0);
        acc1 = __builtin_amdgcn_mfma_f32_16x16x32_bf16(al, bh, acc1, 0, 0, 0);
      }
    }

    // ---- gate exchange. C/D layout: col(n)=lane&15, row=quad*4+r ----
    if (frag_n < 8) {
#pragma unroll
      for (int r = 0; r < 4; ++r) {
        exch[(wave * 32 + quad * 4 + r) * 9 + frag_n]      = acc0[r];
        exch[(wave * 32 + 16 + quad * 4 + r) * 9 + frag_n] = acc1[r];
      }
    }

    lds_barrier();

    // ---- elementwise LSTM cell update; thread (eb, ei) owns c persistently ----
    {
      float X0 = exch[(0 * 32 + ei) * 9 + eb];
      float X1 = exch[(1 * 32 + ei) * 9 + eb];
      float X2 = exch[(2 * 32 + ei) * 9 + eb];
      float X3 = exch[(3 * 32 + ei) * 9 + eb];
      float ig = fast_sigmoid(X0);
      float fg = fast_sigmoid(X1);
      float gg = fast_tanh(X2);
      float og = fast_sigmoid(X3);
      c_state = fg * c_state + ig * gg;
      float hval = og * fast_tanh(c_state);
      if (t == T_STEPS - 1) {
        out[((size_t)(q * 8 + eb) * C_CH + c) * D_OUT + ei] = hval;
      } else {
        // write h back into B-fragment rows k=32+i as packed hi/lo bf16
        uint32_t u  = __float_as_uint(hval);
        float    r  = hval - __uint_as_float(u & 0xFFFF0000u);
        uint32_t ru = __float_as_uint(r);
        uint32_t pu  = __shfl_xor(u, 1, 64);
        uint32_t pru = __shfl_xor(ru, 1, 64);
        if ((ei & 1) == 0) {
          *(uint32_t*)&Bhi[eb * RS + 32 + ei] = pack_hi16(u, pu);
          *(uint32_t*)&Blo[eb * RS + 32 + ei] = pack_hi16(ru, pru);
        }
      }
    }
    // h-writes are ordered before next iteration's MFMA reads by the first
    // lds_barrier of iteration t+1; next iteration's staging writes touch
    // disjoint LDS regions (A planes, B rows k<32), so no extra barrier.
  }
}

extern "C" void kernel_launch(void* const* d_in, const int* in_sizes, int n_in,
                              void* d_out, int out_size, void* d_ws, size_t ws_size,
                              hipStream_t stream) {
  const float* x    = (const float*)d_in[0];
  const float* xOps = (const float*)d_in[1];
  const float* hOps = (const float*)d_in[2];
  lstm_kernel<<<dim3(256), dim3(256), 0, stream>>>(x, xOps, hOps, (float*)d_out);
}